// Round 7
// baseline (341.608 us; speedup 1.0000x reference)
//
#include <hip/hip_runtime.h>
#include <hip/hip_bf16.h>
#include <hip/hip_cooperative_groups.h>

namespace cg = cooperative_groups;

#define B_ 2
#define T_ 1024
#define D_ 1024
#define H_ 8
#define DEPTH_ 5
#define DH_ 128

typedef short s16x8 __attribute__((ext_vector_type(8)));
typedef short s16x4 __attribute__((ext_vector_type(4)));
typedef float f32x4 __attribute__((ext_vector_type(4)));

__device__ inline short f2bf(float f) {
  __hip_bfloat16 h = __float2bfloat16(f);
  return *reinterpret_cast<short*>(&h);
}

#define MFMA16(a, b, c) __builtin_amdgcn_mfma_f32_16x16x32_bf16(a, b, c, 0, 0, 0)

// -------------------------------------------------------------------------
// Prep (one launch, grid (16,16,4), 256 threads):
//  z=0: Wv[K][N] -> Wvt[n][k] bf16     z=1: Wo -> Wot[n][k] bf16
//  z=2: x fp32 -> xb bf16 (streaming)
//  z=3 (blocks 0..31): paths = sigmoid(x @ Wp + bp) via MFMA,
//       64-row tiles, Wp staged transposed into LDS each K-step.
// -------------------------------------------------------------------------
__global__ __launch_bounds__(256) void prep_kernel(
    const float* __restrict__ Wv, const float* __restrict__ Wo,
    const float* __restrict__ Wp, const float* __restrict__ bp,
    const float* __restrict__ x, short* __restrict__ Wvt,
    short* __restrict__ Wot, short* __restrict__ xb,
    float* __restrict__ paths_t) {
  int tid = threadIdx.x;
  if (blockIdx.z < 2) {
    const float* W = blockIdx.z ? Wo : Wv;
    short* Wt = blockIdx.z ? Wot : Wvt;
    __shared__ float tile[64][65];
    int k0 = blockIdx.y * 64, n0 = blockIdx.x * 64;
#pragma unroll
    for (int i = 0; i < 4; ++i) {
      int idx = tid + i * 256;
      int r = idx >> 4, c4 = (idx & 15) * 4;
      float4 v = *(const float4*)&W[(size_t)(k0 + r) * D_ + n0 + c4];
      tile[r][c4 + 0] = v.x;
      tile[r][c4 + 1] = v.y;
      tile[r][c4 + 2] = v.z;
      tile[r][c4 + 3] = v.w;
    }
    __syncthreads();
#pragma unroll
    for (int j = 0; j < 2; ++j) {
      int idx = tid + j * 256;
      int n = idx >> 3, k8 = (idx & 7) * 8;
      s16x8 outv;
#pragma unroll
      for (int jj = 0; jj < 8; ++jj) outv[jj] = f2bf(tile[k8 + jj][n]);
      *(s16x8*)&Wt[(size_t)(n0 + n) * D_ + k0 + k8] = outv;
    }
  } else if (blockIdx.z == 2) {
    int bid = blockIdx.y * 16 + blockIdx.x;  // 0..255
#pragma unroll
    for (int c = 0; c < 4; ++c) {
      size_t idx = (size_t)bid * 8192 + c * 2048 + tid * 8;
      float4 f0 = *(const float4*)&x[idx];
      float4 f1 = *(const float4*)&x[idx + 4];
      s16x8 v;
      v[0] = f2bf(f0.x); v[1] = f2bf(f0.y);
      v[2] = f2bf(f0.z); v[3] = f2bf(f0.w);
      v[4] = f2bf(f1.x); v[5] = f2bf(f1.y);
      v[6] = f2bf(f1.z); v[7] = f2bf(f1.w);
      *(s16x8*)&xb[idx] = v;
    }
  } else {
    int bid = blockIdx.y * 16 + blockIdx.x;
    if (bid >= 32) return;  // 32 blocks, 64 rows each
    __shared__ short As[64 * 72];
    __shared__ short Bs[64 * 72];
    int w = tid >> 6, lane = tid & 63;
    int g = lane >> 4, fr = lane & 15;
    int wm = (w >> 1) * 32, wn = (w & 1) * 32;
    int bm = bid * 64;
    f32x4 acc[2][2] = {{{0.f, 0.f, 0.f, 0.f}, {0.f, 0.f, 0.f, 0.f}},
                       {{0.f, 0.f, 0.f, 0.f}, {0.f, 0.f, 0.f, 0.f}}};
    for (int k0 = 0; k0 < D_; k0 += 64) {
      s16x8 av[2];
#pragma unroll
      for (int i = 0; i < 2; ++i) {
        int c = tid + i * 256;
        int row = c >> 3, ko = (c & 7) * 8;
        const float* p = &x[(size_t)(bm + row) * D_ + k0 + ko];
        float4 f0 = *(const float4*)p, f1 = *(const float4*)(p + 4);
        av[i][0] = f2bf(f0.x); av[i][1] = f2bf(f0.y);
        av[i][2] = f2bf(f0.z); av[i][3] = f2bf(f0.w);
        av[i][4] = f2bf(f1.x); av[i][5] = f2bf(f1.y);
        av[i][6] = f2bf(f1.z); av[i][7] = f2bf(f1.w);
      }
      short bv[16];
#pragma unroll
      for (int j = 0; j < 16; ++j) {
        int e = tid + j * 256;
        int n = e & 63, r = e >> 6;
        bv[j] = (n < H_ * DEPTH_) ? f2bf(Wp[(size_t)(k0 + r) * (H_ * DEPTH_) + n])
                                  : (short)0;
      }
      __syncthreads();
#pragma unroll
      for (int i = 0; i < 2; ++i) {
        int c = tid + i * 256;
        int row = c >> 3, ko = (c & 7) * 8;
        *(s16x8*)&As[row * 72 + ko] = av[i];
      }
#pragma unroll
      for (int j = 0; j < 16; ++j) {
        int e = tid + j * 256;
        int n = e & 63, r = e >> 6;
        Bs[n * 72 + r] = bv[j];
      }
      __syncthreads();
#pragma unroll
      for (int ks = 0; ks < 2; ++ks) {
        int ko = ks * 32 + g * 8;
        s16x8 a0 = *(const s16x8*)&As[(wm + fr) * 72 + ko];
        s16x8 a1 = *(const s16x8*)&As[(wm + 16 + fr) * 72 + ko];
        s16x8 b0 = *(const s16x8*)&Bs[(wn + fr) * 72 + ko];
        s16x8 b1 = *(const s16x8*)&Bs[(wn + 16 + fr) * 72 + ko];
        acc[0][0] = MFMA16(a0, b0, acc[0][0]);
        acc[0][1] = MFMA16(a0, b1, acc[0][1]);
        acc[1][0] = MFMA16(a1, b0, acc[1][0]);
        acc[1][1] = MFMA16(a1, b1, acc[1][1]);
      }
    }
    int col = fr, rbase = g * 4;
#pragma unroll
    for (int ni = 0; ni < 2; ++ni) {
      int pn = wn + ni * 16 + col;  // 0..63
      if (pn < H_ * DEPTH_) {
        float bias = bp[pn];
        int h = pn / DEPTH_, d = pn % DEPTH_;
#pragma unroll
        for (int mi = 0; mi < 2; ++mi)
#pragma unroll
          for (int r = 0; r < 4; ++r) {
            int m = bm + wm + mi * 16 + rbase + r;
            int b = m >> 10, t = m & (T_ - 1);
            float pv = 1.f / (1.f + __expf(-(acc[mi][ni][r] + bias)));
            paths_t[(((size_t)(b * H_ + h) * T_ + t) * DEPTH_) + d] = pv;
          }
      }
    }
  }
}

// -------------------------------------------------------------------------
// Fused cooperative kernel: 256 blocks x 512 threads, 1 block/CU.
//  stage A: Vt[bh][dh][t] = (xb @ Wvt^T) transposed-bf16; 128x64 tile/block
//  stage B: p-adic causal attention (q-tile pair, KT=128)
//  stage C: out = ctxb @ Wot^T fp32; 128x64 tile/block
// grid.sync() between stages.
// -------------------------------------------------------------------------
#define LS2 136
#define SMEM_BYTES 43648  // max(gemm 27648, attn 43648)

__global__ __launch_bounds__(512) void fused_kernel(
    const short* __restrict__ xb, const short* __restrict__ Wvt,
    short* __restrict__ Vt, const float* __restrict__ paths_t,
    const short* __restrict__ Wot, short* __restrict__ ctxb,
    float* __restrict__ outp) {
  cg::grid_group grid = cg::this_grid();
  __shared__ __align__(16) char smem[SMEM_BYTES];
  int tid = threadIdx.x;
  int w = tid >> 6, lane = tid & 63;
  int g = lane >> 4, fr = lane & 15;
  int u = blockIdx.x;

  // ---------------- stage A: V-GEMM ----------------
  {
    short* As = (short*)smem;        // [128][72]
    short* Bs = As + 128 * 72;       // [64][72]
    int bm = (u & 15) << 7, bn = (u >> 4) << 6;
    int wm = (w >> 1) * 32, wn = (w & 1) * 32;
    int srow = tid >> 3, sko = (tid & 7) * 8;
    f32x4 acc[2][2] = {{{0.f, 0.f, 0.f, 0.f}, {0.f, 0.f, 0.f, 0.f}},
                       {{0.f, 0.f, 0.f, 0.f}, {0.f, 0.f, 0.f, 0.f}}};
    for (int k0 = 0; k0 < D_; k0 += 64) {
      s16x8 av0 = *(const s16x8*)&xb[(size_t)(bm + srow) * D_ + k0 + sko];
      s16x8 av1 = *(const s16x8*)&xb[(size_t)(bm + 64 + srow) * D_ + k0 + sko];
      s16x8 bv = *(const s16x8*)&Wvt[(size_t)(bn + srow) * D_ + k0 + sko];
      __syncthreads();
      *(s16x8*)&As[srow * 72 + sko] = av0;
      *(s16x8*)&As[(64 + srow) * 72 + sko] = av1;
      *(s16x8*)&Bs[srow * 72 + sko] = bv;
      __syncthreads();
#pragma unroll
      for (int ks = 0; ks < 2; ++ks) {
        int ko = ks * 32 + g * 8;
        s16x8 a0 = *(const s16x8*)&As[(wm + fr) * 72 + ko];
        s16x8 a1 = *(const s16x8*)&As[(wm + 16 + fr) * 72 + ko];
        s16x8 b0 = *(const s16x8*)&Bs[(wn + fr) * 72 + ko];
        s16x8 b1 = *(const s16x8*)&Bs[(wn + 16 + fr) * 72 + ko];
        acc[0][0] = MFMA16(a0, b0, acc[0][0]);
        acc[0][1] = MFMA16(a0, b1, acc[0][1]);
        acc[1][0] = MFMA16(a1, b0, acc[1][0]);
        acc[1][1] = MFMA16(a1, b1, acc[1][1]);
      }
    }
    int col = fr, rbase = g * 4;
#pragma unroll
    for (int mi = 0; mi < 2; ++mi)
#pragma unroll
      for (int ni = 0; ni < 2; ++ni) {
        int m = bm + wm + mi * 16 + rbase;  // 4 consecutive t
        int n = bn + wn + ni * 16 + col;    // dh col
        int b = m >> 10, t = m & (T_ - 1);
        int h = n >> 7, dh = n & (DH_ - 1);
        s16x4 v4;
#pragma unroll
        for (int r = 0; r < 4; ++r) v4[r] = f2bf(acc[mi][ni][r]);
        *(s16x4*)&Vt[((size_t)((b * H_ + h) * DH_ + dh)) * T_ + t] = v4;
      }
  }
  __threadfence();
  grid.sync();

  // ---------------- stage B: attention ----------------
  {
    short* Vs = (short*)smem;             // [128][136]
    short* Ss = Vs + DH_ * LS2;           // [32][136]
    float* lsum_s = (float*)(Ss + 32 * LS2);
    int bh = u >> 4, bx = u & 15;
    int b = bh >> 3, h = bh & 7;
    const float* pb = paths_t + (size_t)bh * T_ * DEPTH_;
    const short* vb = Vt + (size_t)bh * DH_ * T_;

    for (int half = 0; half < 2; ++half) {
      int qt = half ? (31 - bx) : bx;
      int q0 = qt * 32;
      int nkt = (qt >> 2) + 1;  // KT=128 tiles; pair total = 9 always

      float pq[4][DEPTH_], mq[4][DEPTH_];
#pragma unroll
      for (int j = 0; j < 4; ++j) {
        const float* qr = pb + (size_t)(q0 + w * 4 + j) * DEPTH_;
#pragma unroll
        for (int d = 0; d < DEPTH_; ++d) {
          pq[j][d] = qr[d];
          mq[j][d] = 1.f - pq[j][d];
        }
      }
      f32x4 acc[2] = {{0.f, 0.f, 0.f, 0.f}, {0.f, 0.f, 0.f, 0.f}};
      float part[4] = {};

      for (int kt = 0; kt < nkt; ++kt) {
        int k0 = kt * 128;
        __syncthreads();
#pragma unroll
        for (int i = 0; i < 4; ++i) {
          int c = tid + i * 512;
          int dh = c >> 4, ko = (c & 15) * 8;
          *(s16x8*)&Vs[dh * LS2 + ko] =
              *(const s16x8*)&vb[(size_t)dh * T_ + k0 + ko];
        }
        int kA = k0 + lane, kB = k0 + 64 + lane;
        const float* krA = pb + (size_t)kA * DEPTH_;
        const float* krB = pb + (size_t)kB * DEPTH_;
        float pkA[DEPTH_], mkA[DEPTH_], pkB[DEPTH_], mkB[DEPTH_];
#pragma unroll
        for (int d = 0; d < DEPTH_; ++d) {
          pkA[d] = krA[d]; mkA[d] = 1.f - pkA[d];
          pkB[d] = krB[d]; mkB[d] = 1.f - pkB[d];
        }
#pragma unroll
        for (int j = 0; j < 4; ++j) {
          int qg = q0 + w * 4 + j;
          {
            float a0 = fmaf(pq[j][0], pkA[0], mq[j][0] * mkA[0]);
            float a1 = fmaf(pq[j][1], pkA[1], mq[j][1] * mkA[1]);
            float a2 = fmaf(pq[j][2], pkA[2], mq[j][2] * mkA[2]);
            float a3 = fmaf(pq[j][3], pkA[3], mq[j][3] * mkA[3]);
            float a4 = fmaf(pq[j][4], pkA[4], mq[j][4] * mkA[4]);
            float t4 = 1.f + a4;
            float t3 = fmaf(a3, t4, 1.f);
            float t2 = fmaf(a2, t3, 1.f);
            float t1 = fmaf(a1, t2, 1.f);
            float s = a0 * t1;
            float wv = (kA <= qg) ? __expf(s * 0.2f) : 0.f;
            part[j] += wv;
            Ss[(w * 4 + j) * LS2 + lane] = f2bf(wv);
          }
          {
            float a0 = fmaf(pq[j][0], pkB[0], mq[j][0] * mkB[0]);
            float a1 = fmaf(pq[j][1], pkB[1], mq[j][1] * mkB[1]);
            float a2 = fmaf(pq[j][2], pkB[2], mq[j][2] * mkB[2]);
            float a3 = fmaf(pq[j][3], pkB[3], mq[j][3] * mkB[3]);
            float a4 = fmaf(pq[j][4], pkB[4], mq[j][4] * mkB[4]);
            float t4 = 1.f + a4;
            float t3 = fmaf(a3, t4, 1.f);
            float t2 = fmaf(a2, t3, 1.f);
            float t1 = fmaf(a1, t2, 1.f);
            float s = a0 * t1;
            float wv = (kB <= qg) ? __expf(s * 0.2f) : 0.f;
            part[j] += wv;
            Ss[(w * 4 + j) * LS2 + 64 + lane] = f2bf(wv);
          }
        }
        __syncthreads();
#pragma unroll
        for (int ks = 0; ks < 4; ++ks) {
          int ko = ks * 32 + g * 8;
          s16x8 sa0 = *(const s16x8*)&Ss[fr * LS2 + ko];
          s16x8 sa1 = *(const s16x8*)&Ss[(16 + fr) * LS2 + ko];
          s16x8 vv = *(const s16x8*)&Vs[(w * 16 + fr) * LS2 + ko];
          acc[0] = MFMA16(sa0, vv, acc[0]);
          acc[1] = MFMA16(sa1, vv, acc[1]);
        }
      }
#pragma unroll
      for (int j = 0; j < 4; ++j) {
        float s = part[j];
#pragma unroll
        for (int off = 32; off >= 1; off >>= 1) s += __shfl_xor(s, off, 64);
        if (lane == j) lsum_s[w * 4 + j] = s;
      }
      __syncthreads();
      int col = fr, rbase = g * 4;
#pragma unroll
      for (int qt2 = 0; qt2 < 2; ++qt2)
#pragma unroll
        for (int r = 0; r < 4; ++r) {
          int ql = qt2 * 16 + rbase + r;
          int dh = w * 16 + col;
          float val = acc[qt2][r] / lsum_s[ql];
          ctxb[(size_t)(b * T_ + q0 + ql) * D_ + h * DH_ + dh] = f2bf(val);
        }
      __syncthreads();  // protect lsum_s/Ss before next half re-stages
    }
  }
  __threadfence();
  grid.sync();

  // ---------------- stage C: out-GEMM ----------------
  {
    short* As = (short*)smem;
    short* Bs = As + 128 * 72;
    int bm = (u & 15) << 7, bn = (u >> 4) << 6;
    int wm = (w >> 1) * 32, wn = (w & 1) * 32;
    int srow = tid >> 3, sko = (tid & 7) * 8;
    f32x4 acc[2][2] = {{{0.f, 0.f, 0.f, 0.f}, {0.f, 0.f, 0.f, 0.f}},
                       {{0.f, 0.f, 0.f, 0.f}, {0.f, 0.f, 0.f, 0.f}}};
    for (int k0 = 0; k0 < D_; k0 += 64) {
      s16x8 av0 = *(const s16x8*)&ctxb[(size_t)(bm + srow) * D_ + k0 + sko];
      s16x8 av1 =
          *(const s16x8*)&ctxb[(size_t)(bm + 64 + srow) * D_ + k0 + sko];
      s16x8 bv = *(const s16x8*)&Wot[(size_t)(bn + srow) * D_ + k0 + sko];
      __syncthreads();
      *(s16x8*)&As[srow * 72 + sko] = av0;
      *(s16x8*)&As[(64 + srow) * 72 + sko] = av1;
      *(s16x8*)&Bs[srow * 72 + sko] = bv;
      __syncthreads();
#pragma unroll
      for (int ks = 0; ks < 2; ++ks) {
        int ko = ks * 32 + g * 8;
        s16x8 a0 = *(const s16x8*)&As[(wm + fr) * 72 + ko];
        s16x8 a1 = *(const s16x8*)&As[(wm + 16 + fr) * 72 + ko];
        s16x8 b0 = *(const s16x8*)&Bs[(wn + fr) * 72 + ko];
        s16x8 b1 = *(const s16x8*)&Bs[(wn + 16 + fr) * 72 + ko];
        acc[0][0] = MFMA16(a0, b0, acc[0][0]);
        acc[0][1] = MFMA16(a0, b1, acc[0][1]);
        acc[1][0] = MFMA16(a1, b0, acc[1][0]);
        acc[1][1] = MFMA16(a1, b1, acc[1][1]);
      }
    }
    int col = fr, rbase = g * 4;
#pragma unroll
    for (int mi = 0; mi < 2; ++mi)
#pragma unroll
      for (int ni = 0; ni < 2; ++ni)
#pragma unroll
        for (int r = 0; r < 4; ++r)
          outp[(size_t)(bm + wm + mi * 16 + rbase + r) * D_ + bn + wn +
               ni * 16 + col] = acc[mi][ni][r];
  }
}

// -------------------------------------------------------------------------
extern "C" void kernel_launch(void* const* d_in, const int* in_sizes, int n_in,
                              void* d_out, int out_size, void* d_ws,
                              size_t ws_size, hipStream_t stream) {
  const float* x = (const float*)d_in[0];
  const float* Wp = (const float*)d_in[1];
  const float* bp = (const float*)d_in[2];
  const float* Wv = (const float*)d_in[3];
  const float* Wo = (const float*)d_in[4];
  float* out = (float*)d_out;

  char* ws = (char*)d_ws;
  float* paths_t = (float*)ws;             //   327,680 B
  short* Vt = (short*)(ws + 327680);       // 4,194,304 B bf16 [bh][dh][t]
  short* Wvt = (short*)(ws + 4521984);     // 2,097,152 B bf16 [1024][1024]
  short* Wot = (short*)(ws + 6619136);     // 2,097,152 B bf16 [1024][1024]
  short* ctxb = (short*)(ws + 8716288);    // 4,194,304 B bf16 [2048][1024]
  short* xb = (short*)(ws + 12910592);     // 4,194,304 B bf16 [2048][1024]
  // total ~17.1 MB

  prep_kernel<<<dim3(16, 16, 4), 256, 0, stream>>>(Wv, Wo, Wp, bp, x, Wvt,
                                                   Wot, xb, paths_t);
  void* kargs[] = {(void*)&xb,  (void*)&Wvt,  (void*)&Vt, (void*)&paths_t,
                   (void*)&Wot, (void*)&ctxb, (void*)&out};
  hipLaunchCooperativeKernel((void*)fused_kernel, dim3(256), dim3(512), kargs,
                             0, stream);
}

// Round 8
// 183.267 us; speedup vs baseline: 1.8640x; 1.8640x over previous
//
#include <hip/hip_runtime.h>
#include <hip/hip_bf16.h>

#define B_ 2
#define T_ 1024
#define D_ 1024
#define H_ 8
#define DEPTH_ 5
#define DH_ 128

typedef short s16x8 __attribute__((ext_vector_type(8)));
typedef short s16x4 __attribute__((ext_vector_type(4)));
typedef float f32x4 __attribute__((ext_vector_type(4)));

__device__ inline short f2bf(float f) {
  __hip_bfloat16 h = __float2bfloat16(f);
  return *reinterpret_cast<short*>(&h);
}

#define MFMA16(a, b, c) __builtin_amdgcn_mfma_f32_16x16x32_bf16(a, b, c, 0, 0, 0)

// global -> LDS async copy, 16B/lane. LDS dest = wave-uniform base + lane*16.
typedef __attribute__((address_space(3))) unsigned int lds_u32_t;
typedef __attribute__((address_space(1))) unsigned int glb_u32_t;
__device__ __forceinline__ void glds16(const void* g, void* l) {
  __builtin_amdgcn_global_load_lds((const glb_u32_t*)g, (lds_u32_t*)l, 16, 0,
                                   0);
}

// -------------------------------------------------------------------------
// Prep (one launch, grid (16,16,4), 256 threads):
//  z=0: Wv[K][N] -> Wvt[n][k] bf16     z=1: Wo -> Wot[n][k] bf16
//  z=2: x fp32 -> xb bf16 (streaming)
//  z=3 (blocks 0..31): paths = sigmoid(x @ Wp + bp) via MFMA.
// -------------------------------------------------------------------------
__global__ __launch_bounds__(256) void prep_kernel(
    const float* __restrict__ Wv, const float* __restrict__ Wo,
    const float* __restrict__ Wp, const float* __restrict__ bp,
    const float* __restrict__ x, short* __restrict__ Wvt,
    short* __restrict__ Wot, short* __restrict__ xb,
    float* __restrict__ paths_t) {
  int tid = threadIdx.x;
  if (blockIdx.z < 2) {
    const float* W = blockIdx.z ? Wo : Wv;
    short* Wt = blockIdx.z ? Wot : Wvt;
    __shared__ float tile[64][65];
    int k0 = blockIdx.y * 64, n0 = blockIdx.x * 64;
#pragma unroll
    for (int i = 0; i < 4; ++i) {
      int idx = tid + i * 256;
      int r = idx >> 4, c4 = (idx & 15) * 4;
      float4 v = *(const float4*)&W[(size_t)(k0 + r) * D_ + n0 + c4];
      tile[r][c4 + 0] = v.x;
      tile[r][c4 + 1] = v.y;
      tile[r][c4 + 2] = v.z;
      tile[r][c4 + 3] = v.w;
    }
    __syncthreads();
#pragma unroll
    for (int j = 0; j < 2; ++j) {
      int idx = tid + j * 256;
      int n = idx >> 3, k8 = (idx & 7) * 8;
      s16x8 outv;
#pragma unroll
      for (int jj = 0; jj < 8; ++jj) outv[jj] = f2bf(tile[k8 + jj][n]);
      *(s16x8*)&Wt[(size_t)(n0 + n) * D_ + k0 + k8] = outv;
    }
  } else if (blockIdx.z == 2) {
    int bid = blockIdx.y * 16 + blockIdx.x;  // 0..255
#pragma unroll
    for (int c = 0; c < 4; ++c) {
      size_t idx = (size_t)bid * 8192 + c * 2048 + tid * 8;
      float4 f0 = *(const float4*)&x[idx];
      float4 f1 = *(const float4*)&x[idx + 4];
      s16x8 v;
      v[0] = f2bf(f0.x); v[1] = f2bf(f0.y);
      v[2] = f2bf(f0.z); v[3] = f2bf(f0.w);
      v[4] = f2bf(f1.x); v[5] = f2bf(f1.y);
      v[6] = f2bf(f1.z); v[7] = f2bf(f1.w);
      *(s16x8*)&xb[idx] = v;
    }
  } else {
    int bid = blockIdx.y * 16 + blockIdx.x;
    if (bid >= 32) return;  // 32 blocks x 64 rows
    __shared__ short As[64 * 72];
    __shared__ short Bs[64 * 72];
    int w = tid >> 6, lane = tid & 63;
    int g = lane >> 4, fr = lane & 15;
    int wm = (w >> 1) * 32, wn = (w & 1) * 32;
    int bm = bid * 64;
    f32x4 acc[2][2] = {{{0.f, 0.f, 0.f, 0.f}, {0.f, 0.f, 0.f, 0.f}},
                       {{0.f, 0.f, 0.f, 0.f}, {0.f, 0.f, 0.f, 0.f}}};
    for (int k0 = 0; k0 < D_; k0 += 64) {
      s16x8 av[2];
#pragma unroll
      for (int i = 0; i < 2; ++i) {
        int c = tid + i * 256;
        int row = c >> 3, ko = (c & 7) * 8;
        const float* p = &x[(size_t)(bm + row) * D_ + k0 + ko];
        float4 f0 = *(const float4*)p, f1 = *(const float4*)(p + 4);
        av[i][0] = f2bf(f0.x); av[i][1] = f2bf(f0.y);
        av[i][2] = f2bf(f0.z); av[i][3] = f2bf(f0.w);
        av[i][4] = f2bf(f1.x); av[i][5] = f2bf(f1.y);
        av[i][6] = f2bf(f1.z); av[i][7] = f2bf(f1.w);
      }
      short bv[16];
#pragma unroll
      for (int j = 0; j < 16; ++j) {
        int e = tid + j * 256;
        int n = e & 63, r = e >> 6;
        bv[j] = (n < H_ * DEPTH_)
                    ? f2bf(Wp[(size_t)(k0 + r) * (H_ * DEPTH_) + n])
                    : (short)0;
      }
      __syncthreads();
#pragma unroll
      for (int i = 0; i < 2; ++i) {
        int c = tid + i * 256;
        int row = c >> 3, ko = (c & 7) * 8;
        *(s16x8*)&As[row * 72 + ko] = av[i];
      }
#pragma unroll
      for (int j = 0; j < 16; ++j) {
        int e = tid + j * 256;
        int n = e & 63, r = e >> 6;
        Bs[n * 72 + r] = bv[j];
      }
      __syncthreads();
#pragma unroll
      for (int ks = 0; ks < 2; ++ks) {
        int ko = ks * 32 + g * 8;
        s16x8 a0 = *(const s16x8*)&As[(wm + fr) * 72 + ko];
        s16x8 a1 = *(const s16x8*)&As[(wm + 16 + fr) * 72 + ko];
        s16x8 b0 = *(const s16x8*)&Bs[(wn + fr) * 72 + ko];
        s16x8 b1 = *(const s16x8*)&Bs[(wn + 16 + fr) * 72 + ko];
        acc[0][0] = MFMA16(a0, b0, acc[0][0]);
        acc[0][1] = MFMA16(a0, b1, acc[0][1]);
        acc[1][0] = MFMA16(a1, b0, acc[1][0]);
        acc[1][1] = MFMA16(a1, b1, acc[1][1]);
      }
    }
    int col = fr, rbase = g * 4;
#pragma unroll
    for (int ni = 0; ni < 2; ++ni) {
      int pn = wn + ni * 16 + col;  // 0..63
      if (pn < H_ * DEPTH_) {
        float bias = bp[pn];
        int h = pn / DEPTH_, d = pn % DEPTH_;
#pragma unroll
        for (int mi = 0; mi < 2; ++mi)
#pragma unroll
          for (int r = 0; r < 4; ++r) {
            int m = bm + wm + mi * 16 + rbase + r;
            int b = m >> 10, t = m & (T_ - 1);
            float pv = 1.f / (1.f + __expf(-(acc[mi][ni][r] + bias)));
            paths_t[(((size_t)(b * H_ + h) * T_ + t) * DEPTH_) + d] = pv;
          }
      }
    }
  }
}

// -------------------------------------------------------------------------
// MFMA bf16 GEMM, 64x64 tile, BK=128, glds16 staging into unpadded LDS
// with XOR source swizzle (logical colgroup g of row r at physical
// g^(r&15)). 4 waves (2x2), wave tile 32x32, 16 MFMA/wave/iter.
// C/D: col=lane&15, row=(lane>>4)*4+reg.
// MODE 0: fp32 C[M][1024].  MODE 1: Vt bf16 [bh][dh][t].
// -------------------------------------------------------------------------
template <int MODE>
__global__ __launch_bounds__(256) void gemm128(
    const short* __restrict__ A, const short* __restrict__ Bt,
    float* __restrict__ Cf, short* __restrict__ Vt) {
  __shared__ short As[64 * 128];  // 16 KB
  __shared__ short Bs[64 * 128];  // 16 KB
  const int K = D_;
  int tid = threadIdx.x;
  int bm = blockIdx.y << 6, bn = blockIdx.x << 6;
  int w = tid >> 6, lane = tid & 63;
  int wm = (w >> 1) * 32, wn = (w & 1) * 32;
  int g = lane >> 4, fr = lane & 15;
  f32x4 acc[2][2] = {{{0.f, 0.f, 0.f, 0.f}, {0.f, 0.f, 0.f, 0.f}},
                     {{0.f, 0.f, 0.f, 0.f}, {0.f, 0.f, 0.f, 0.f}}};

  // staging: wave w owns rows [w*16, w*16+16); glds i covers rows w*16+i*4..+3
  int r4 = lane >> 4;  // row within 4-row chunk
  int cg = lane & 15;  // dest physical colgroup
  const short* Asrc[4];
  const short* Bsrc[4];
  short* Adst[4];
  short* Bdst[4];
#pragma unroll
  for (int i = 0; i < 4; ++i) {
    int row = w * 16 + i * 4 + r4;
    int scol = (cg ^ (row & 15)) * 8;  // source colgroup (XOR swizzle)
    Asrc[i] = A + (size_t)(bm + row) * K + scol;
    Bsrc[i] = Bt + (size_t)(bn + row) * K + scol;
    Adst[i] = &As[(w * 16 + i * 4) * 128];
    Bdst[i] = &Bs[(w * 16 + i * 4) * 128];
  }

  for (int k0 = 0; k0 < K; k0 += 128) {
    __syncthreads();  // previous iteration's fragment readers done
#pragma unroll
    for (int i = 0; i < 4; ++i) {
      glds16(Asrc[i] + k0, Adst[i]);
      glds16(Bsrc[i] + k0, Bdst[i]);
    }
    __syncthreads();  // drains vmcnt -> staged data visible
#pragma unroll
    for (int ks = 0; ks < 4; ++ks) {
      int p = ((ks * 4 + g) ^ fr) * 8;  // physical slot (rows used: row&15==fr)
      s16x8 a0 = *(const s16x8*)&As[(wm + fr) * 128 + p];
      s16x8 a1 = *(const s16x8*)&As[(wm + 16 + fr) * 128 + p];
      s16x8 b0 = *(const s16x8*)&Bs[(wn + fr) * 128 + p];
      s16x8 b1 = *(const s16x8*)&Bs[(wn + 16 + fr) * 128 + p];
      acc[0][0] = MFMA16(a0, b0, acc[0][0]);
      acc[0][1] = MFMA16(a0, b1, acc[0][1]);
      acc[1][0] = MFMA16(a1, b0, acc[1][0]);
      acc[1][1] = MFMA16(a1, b1, acc[1][1]);
    }
  }
  int col = lane & 15, rbase = (lane >> 4) * 4;
  if (MODE == 0) {
#pragma unroll
    for (int mi = 0; mi < 2; ++mi)
#pragma unroll
      for (int ni = 0; ni < 2; ++ni)
#pragma unroll
        for (int r = 0; r < 4; ++r)
          Cf[(size_t)(bm + wm + mi * 16 + rbase + r) * D_ + bn + wn +
             ni * 16 + col] = acc[mi][ni][r];
  } else {
    // V epilogue: bf16, transposed [bh][dh][t]
#pragma unroll
    for (int mi = 0; mi < 2; ++mi)
#pragma unroll
      for (int ni = 0; ni < 2; ++ni) {
        int m = bm + wm + mi * 16 + rbase;  // t start (4 consecutive)
        int n = bn + wn + ni * 16 + col;    // dh col
        int b = m >> 10, t = m & (T_ - 1);
        int h = n >> 7, dh = n & (DH_ - 1);
        s16x4 v4;
#pragma unroll
        for (int r = 0; r < 4; ++r) v4[r] = f2bf(acc[mi][ni][r]);
        *(s16x4*)&Vt[((size_t)((b * H_ + h) * DH_ + dh)) * T_ + t] = v4;
      }
  }
}

// -------------------------------------------------------------------------
// Fused causal p-adic attention, MFMA P.V.  512 threads / 8 waves.
// KT=128: 9 k-tiles per block-pair (qt/4 + (31-qt)/4 + 2 == 9 for all qt).
// V tile staged via global_load_lds into unpadded Vs[128][128] with XOR
// source swizzle (conflict-free DMA writes, 2-way frag reads).
// Wave w owns dh strip [w*16, w*16+16) and sim rows q0+w*4..+3; each lane
// computes sim for 2 k-columns. sim in [0,1] -> no max tracking.
// -------------------------------------------------------------------------
#define LS2 136

__global__ __launch_bounds__(512) void attn_kernel(
    const float* __restrict__ paths_t, const short* __restrict__ Vt,
    short* __restrict__ ctxb) {
  int bh = blockIdx.y;  // 0..15
  int b = bh >> 3, h = bh & 7;
  int bx = blockIdx.x;  // 0..15
  int w = threadIdx.x >> 6, lane = threadIdx.x & 63;
  int g = lane >> 4, fr = lane & 15;

  __shared__ short Vs[DH_ * 128];  // [dh][k] unpadded+swizzled, 32 KB
  __shared__ short Ss[32 * LS2];   // [q][k] padded 136, ~8.5 KB
  __shared__ float lsum_s[32];

  const float* pb = paths_t + (size_t)bh * T_ * DEPTH_;
  const short* vb = Vt + (size_t)bh * DH_ * T_;

  // glds addressing (per wave: 4 x 1KB covering rows w*16 .. w*16+15)
  int r4 = lane >> 4, cg = lane & 15;
  const short* Vsrc[4];
  short* Vdst[4];
#pragma unroll
  for (int i = 0; i < 4; ++i) {
    int row = w * 16 + i * 4 + r4;
    int scol = (cg ^ (row & 15)) * 8;
    Vsrc[i] = vb + (size_t)row * T_ + scol;
    Vdst[i] = &Vs[(w * 16 + i * 4) * 128];
  }

  for (int half = 0; half < 2; ++half) {
    int qt = half ? (31 - bx) : bx;
    int q0 = qt * 32;
    int nkt = (qt >> 2) + 1;  // KT=128 tiles; pair total = 9 always

    float pq[4][DEPTH_], mq[4][DEPTH_];
#pragma unroll
    for (int j = 0; j < 4; ++j) {
      const float* qr = pb + (size_t)(q0 + w * 4 + j) * DEPTH_;
#pragma unroll
      for (int d = 0; d < DEPTH_; ++d) {
        pq[j][d] = qr[d];
        mq[j][d] = 1.f - pq[j][d];
      }
    }
    f32x4 acc[2] = {{0.f, 0.f, 0.f, 0.f}, {0.f, 0.f, 0.f, 0.f}};
    float part[4] = {};

    for (int kt = 0; kt < nkt; ++kt) {
      int k0 = kt * 128;
      __syncthreads();  // prev MFMA readers / epilogue done
      // key-path loads first (oldest in vmcnt queue -> sim doesn't wait on glds)
      int kA = k0 + lane, kB = k0 + 64 + lane;
      const float* krA = pb + (size_t)kA * DEPTH_;
      const float* krB = pb + (size_t)kB * DEPTH_;
      float pkA[DEPTH_], mkA[DEPTH_], pkB[DEPTH_], mkB[DEPTH_];
#pragma unroll
      for (int d = 0; d < DEPTH_; ++d) {
        pkA[d] = krA[d];
        pkB[d] = krB[d];
      }
      // V tile DMA: 8 waves x 4 glds = 32 KB
#pragma unroll
      for (int i = 0; i < 4; ++i) glds16(Vsrc[i] + k0, Vdst[i]);
#pragma unroll
      for (int d = 0; d < DEPTH_; ++d) {
        mkA[d] = 1.f - pkA[d];
        mkB[d] = 1.f - pkB[d];
      }
#pragma unroll
      for (int j = 0; j < 4; ++j) {
        int qg = q0 + w * 4 + j;
        {
          float a0 = fmaf(pq[j][0], pkA[0], mq[j][0] * mkA[0]);
          float a1 = fmaf(pq[j][1], pkA[1], mq[j][1] * mkA[1]);
          float a2 = fmaf(pq[j][2], pkA[2], mq[j][2] * mkA[2]);
          float a3 = fmaf(pq[j][3], pkA[3], mq[j][3] * mkA[3]);
          float a4 = fmaf(pq[j][4], pkA[4], mq[j][4] * mkA[4]);
          float t4 = 1.f + a4;
          float t3 = fmaf(a3, t4, 1.f);
          float t2 = fmaf(a2, t3, 1.f);
          float t1 = fmaf(a1, t2, 1.f);
          float s = a0 * t1;
          float wv = (kA <= qg) ? __expf(s * 0.2f) : 0.f;
          part[j] += wv;
          Ss[(w * 4 + j) * LS2 + lane] = f2bf(wv);
        }
        {
          float a0 = fmaf(pq[j][0], pkB[0], mq[j][0] * mkB[0]);
          float a1 = fmaf(pq[j][1], pkB[1], mq[j][1] * mkB[1]);
          float a2 = fmaf(pq[j][2], pkB[2], mq[j][2] * mkB[2]);
          float a3 = fmaf(pq[j][3], pkB[3], mq[j][3] * mkB[3]);
          float a4 = fmaf(pq[j][4], pkB[4], mq[j][4] * mkB[4]);
          float t4 = 1.f + a4;
          float t3 = fmaf(a3, t4, 1.f);
          float t2 = fmaf(a2, t3, 1.f);
          float t1 = fmaf(a1, t2, 1.f);
          float s = a0 * t1;
          float wv = (kB <= qg) ? __expf(s * 0.2f) : 0.f;
          part[j] += wv;
          Ss[(w * 4 + j) * LS2 + 64 + lane] = f2bf(wv);
        }
      }
      __syncthreads();  // drains vmcnt (glds) + lgkm (Ss writes)
      // P @ V via MFMA: wave covers dh [16*w, 16*w+16); 4 ks steps of k32
#pragma unroll
      for (int ks = 0; ks < 4; ++ks) {
        int ko = ks * 32 + g * 8;
        int sl = ((ks * 4 + g) ^ fr) * 8;  // swizzled Vs slot (row&15 == fr)
        s16x8 sa0 = *(const s16x8*)&Ss[fr * LS2 + ko];
        s16x8 sa1 = *(const s16x8*)&Ss[(16 + fr) * LS2 + ko];
        s16x8 vv = *(const s16x8*)&Vs[(w * 16 + fr) * 128 + sl];
        acc[0] = MFMA16(sa0, vv, acc[0]);
        acc[1] = MFMA16(sa1, vv, acc[1]);
      }
    }
    // reduce per-q row sums across the wave's 64 lanes (each lane holds 2 k)
#pragma unroll
    for (int j = 0; j < 4; ++j) {
      float s = part[j];
#pragma unroll
      for (int off = 32; off >= 1; off >>= 1) s += __shfl_xor(s, off, 64);
      if (lane == j) lsum_s[w * 4 + j] = s;
    }
    __syncthreads();
    // epilogue: normalize, write bf16 ctx
    int col = fr, rbase = g * 4;
#pragma unroll
    for (int qt2 = 0; qt2 < 2; ++qt2)
#pragma unroll
      for (int r = 0; r < 4; ++r) {
        int ql = qt2 * 16 + rbase + r;
        int dh = w * 16 + col;
        float val = acc[qt2][r] / lsum_s[ql];
        ctxb[(size_t)(b * T_ + q0 + ql) * D_ + h * DH_ + dh] = f2bf(val);
      }
    __syncthreads();  // protect lsum_s before next half
  }
}

// -------------------------------------------------------------------------
extern "C" void kernel_launch(void* const* d_in, const int* in_sizes, int n_in,
                              void* d_out, int out_size, void* d_ws,
                              size_t ws_size, hipStream_t stream) {
  const float* x = (const float*)d_in[0];
  const float* Wp = (const float*)d_in[1];
  const float* bp = (const float*)d_in[2];
  const float* Wv = (const float*)d_in[3];
  const float* Wo = (const float*)d_in[4];
  float* out = (float*)d_out;

  char* ws = (char*)d_ws;
  float* paths_t = (float*)ws;           //   327,680 B
  short* Vt = (short*)(ws + 327680);     // 4,194,304 B bf16 [bh][dh][t]
  short* Wvt = (short*)(ws + 4521984);   // 2,097,152 B bf16 [1024][1024]
  short* Wot = (short*)(ws + 6619136);   // 2,097,152 B bf16 [1024][1024]
  short* ctxb = (short*)(ws + 8716288);  // 4,194,304 B bf16 [2048][1024]
  short* xb = (short*)(ws + 12910592);   // 4,194,304 B bf16 [2048][1024]
  // total ~17.1 MB

  prep_kernel<<<dim3(16, 16, 4), 256, 0, stream>>>(Wv, Wo, Wp, bp, x, Wvt,
                                                   Wot, xb, paths_t);
  gemm128<1><<<dim3(16, 32), 256, 0, stream>>>(xb, Wvt, nullptr, Vt);
  attn_kernel<<<dim3(16, B_ * H_), 512, 0, stream>>>(paths_t, Vt, ctxb);
  gemm128<0><<<dim3(16, 32), 256, 0, stream>>>(ctxb, Wot, out, nullptr);
}

// Round 9
// 123.045 us; speedup vs baseline: 2.7763x; 1.4894x over previous
//
#include <hip/hip_runtime.h>
#include <hip/hip_bf16.h>

#define B_ 2
#define T_ 1024
#define D_ 1024
#define H_ 8
#define DEPTH_ 5
#define DH_ 128

typedef short s16x8 __attribute__((ext_vector_type(8)));
typedef short s16x4 __attribute__((ext_vector_type(4)));
typedef float f32x4 __attribute__((ext_vector_type(4)));

__device__ inline short f2bf(float f) {
  __hip_bfloat16 h = __float2bfloat16(f);
  return *reinterpret_cast<short*>(&h);
}

#define MFMA16(a, b, c) __builtin_amdgcn_mfma_f32_16x16x32_bf16(a, b, c, 0, 0, 0)

// global -> LDS async copy, 16B/lane. LDS dest = wave-uniform base + lane*16.
typedef __attribute__((address_space(3))) unsigned int lds_u32_t;
typedef __attribute__((address_space(1))) unsigned int glb_u32_t;
__device__ __forceinline__ void glds16(const void* g, void* l) {
  __builtin_amdgcn_global_load_lds((const glb_u32_t*)g, (lds_u32_t*)l, 16, 0,
                                   0);
}

// -------------------------------------------------------------------------
// Prep (one launch, grid (16,16,3), 256 threads) — r6-proven form:
//  z=0: Wv[K][N] -> WBt rows 0..1023 (bf16 [n][k])
//  z=1: Wo -> Wot (bf16 [n][k])
//  z=2: x fp32 -> xb bf16 (streaming); blocks 0..3 also scatter
//       Wp[1024][40] -> WBt rows 1024..1087 (rows >=40 zeroed).
// -------------------------------------------------------------------------
__global__ __launch_bounds__(256) void prep_kernel(
    const float* __restrict__ Wv, const float* __restrict__ Wo,
    const float* __restrict__ Wp, const float* __restrict__ x,
    short* __restrict__ WBt, short* __restrict__ Wot,
    short* __restrict__ xb) {
  int tid = threadIdx.x;
  if (blockIdx.z < 2) {
    const float* W = blockIdx.z ? Wo : Wv;
    short* Wt = blockIdx.z ? Wot : WBt;
    __shared__ float tile[64][65];
    int k0 = blockIdx.y * 64, n0 = blockIdx.x * 64;
#pragma unroll
    for (int i = 0; i < 4; ++i) {
      int idx = tid + i * 256;
      int r = idx >> 4, c4 = (idx & 15) * 4;
      float4 v = *(const float4*)&W[(size_t)(k0 + r) * D_ + n0 + c4];
      tile[r][c4 + 0] = v.x;
      tile[r][c4 + 1] = v.y;
      tile[r][c4 + 2] = v.z;
      tile[r][c4 + 3] = v.w;
    }
    __syncthreads();
#pragma unroll
    for (int j = 0; j < 2; ++j) {
      int idx = tid + j * 256;
      int n = idx >> 3, k8 = (idx & 7) * 8;
      s16x8 outv;
#pragma unroll
      for (int jj = 0; jj < 8; ++jj) outv[jj] = f2bf(tile[k8 + jj][n]);
      *(s16x8*)&Wt[(size_t)(n0 + n) * D_ + k0 + k8] = outv;
    }
  } else {
    int bid = blockIdx.y * 16 + blockIdx.x;  // 0..255
#pragma unroll
    for (int c = 0; c < 4; ++c) {
      size_t idx = (size_t)bid * 8192 + c * 2048 + tid * 8;
      float4 f0 = *(const float4*)&x[idx];
      float4 f1 = *(const float4*)&x[idx + 4];
      s16x8 v;
      v[0] = f2bf(f0.x); v[1] = f2bf(f0.y);
      v[2] = f2bf(f0.z); v[3] = f2bf(f0.w);
      v[4] = f2bf(f1.x); v[5] = f2bf(f1.y);
      v[6] = f2bf(f1.z); v[7] = f2bf(f1.w);
      *(s16x8*)&xb[idx] = v;
    }
    if (bid < 4) {  // Wp rows of WBt
#pragma unroll
      for (int it = 0; it < 8; ++it) {
        int item = bid * 2048 + it * 256 + tid;  // 0..8191
        int row = item >> 7, k8 = (item & 127) * 8;
        s16x8 v;
        if (row < H_ * DEPTH_) {
#pragma unroll
          for (int j = 0; j < 8; ++j)
            v[j] = f2bf(Wp[(size_t)(k8 + j) * (H_ * DEPTH_) + row]);
        } else {
#pragma unroll
          for (int j = 0; j < 8; ++j) v[j] = 0;
        }
        *(s16x8*)&WBt[(size_t)(1024 + row) * D_ + k8] = v;
      }
    }
  }
}

// -------------------------------------------------------------------------
// MFMA bf16 GEMM, 64x64 tile, BK=128, glds16 staging into unpadded LDS
// with XOR source swizzle (logical colgroup g of row r at physical
// g^(r&15)). 4 waves (2x2), wave tile 32x32, 16 MFMA/wave/iter.
// C/D: col=lane&15, row=(lane>>4)*4+reg.
// MODE 0: fp32 C[M][1024].
// MODE 1: Vt bf16 [bh][dh][t]; 17th n-tile (bn==1024) = paths epilogue
//         (sigmoid(z+bp) -> paths_t fp32 (B,H,T,DEPTH)).
// -------------------------------------------------------------------------
template <int MODE>
__global__ __launch_bounds__(256) void gemm128(
    const short* __restrict__ A, const short* __restrict__ Bt,
    float* __restrict__ Cf, short* __restrict__ Vt,
    const float* __restrict__ bp, float* __restrict__ paths_t) {
  __shared__ short As[64 * 128];  // 16 KB
  __shared__ short Bs[64 * 128];  // 16 KB
  const int K = D_;
  int tid = threadIdx.x;
  int bm = blockIdx.y << 6, bn = blockIdx.x << 6;
  int w = tid >> 6, lane = tid & 63;
  int wm = (w >> 1) * 32, wn = (w & 1) * 32;
  int g = lane >> 4, fr = lane & 15;
  f32x4 acc[2][2] = {{{0.f, 0.f, 0.f, 0.f}, {0.f, 0.f, 0.f, 0.f}},
                     {{0.f, 0.f, 0.f, 0.f}, {0.f, 0.f, 0.f, 0.f}}};

  // staging: wave w owns rows [w*16, w*16+16); glds i covers rows w*16+i*4..+3
  int r4 = lane >> 4;  // row within 4-row chunk
  int cg = lane & 15;  // dest physical colgroup
  const short* Asrc[4];
  const short* Bsrc[4];
  short* Adst[4];
  short* Bdst[4];
#pragma unroll
  for (int i = 0; i < 4; ++i) {
    int row = w * 16 + i * 4 + r4;
    int scol = (cg ^ (row & 15)) * 8;  // source colgroup (XOR swizzle)
    Asrc[i] = A + (size_t)(bm + row) * K + scol;
    Bsrc[i] = Bt + (size_t)(bn + row) * K + scol;
    Adst[i] = &As[(w * 16 + i * 4) * 128];
    Bdst[i] = &Bs[(w * 16 + i * 4) * 128];
  }

  for (int k0 = 0; k0 < K; k0 += 128) {
    __syncthreads();  // previous iteration's fragment readers done
#pragma unroll
    for (int i = 0; i < 4; ++i) {
      glds16(Asrc[i] + k0, Adst[i]);
      glds16(Bsrc[i] + k0, Bdst[i]);
    }
    __syncthreads();  // drains vmcnt -> staged data visible
#pragma unroll
    for (int ks = 0; ks < 4; ++ks) {
      int p = ((ks * 4 + g) ^ fr) * 8;  // physical slot (rows used: row&15==fr)
      s16x8 a0 = *(const s16x8*)&As[(wm + fr) * 128 + p];
      s16x8 a1 = *(const s16x8*)&As[(wm + 16 + fr) * 128 + p];
      s16x8 b0 = *(const s16x8*)&Bs[(wn + fr) * 128 + p];
      s16x8 b1 = *(const s16x8*)&Bs[(wn + 16 + fr) * 128 + p];
      acc[0][0] = MFMA16(a0, b0, acc[0][0]);
      acc[0][1] = MFMA16(a0, b1, acc[0][1]);
      acc[1][0] = MFMA16(a1, b0, acc[1][0]);
      acc[1][1] = MFMA16(a1, b1, acc[1][1]);
    }
  }
  int col = lane & 15, rbase = (lane >> 4) * 4;
  if (MODE == 0) {
#pragma unroll
    for (int mi = 0; mi < 2; ++mi)
#pragma unroll
      for (int ni = 0; ni < 2; ++ni)
#pragma unroll
        for (int r = 0; r < 4; ++r)
          Cf[(size_t)(bm + wm + mi * 16 + rbase + r) * D_ + bn + wn +
             ni * 16 + col] = acc[mi][ni][r];
  } else if (bn < 1024) {
    // V epilogue: bf16, transposed [bh][dh][t]
#pragma unroll
    for (int mi = 0; mi < 2; ++mi)
#pragma unroll
      for (int ni = 0; ni < 2; ++ni) {
        int m = bm + wm + mi * 16 + rbase;  // t start (4 consecutive)
        int n = bn + wn + ni * 16 + col;    // dh col
        int b = m >> 10, t = m & (T_ - 1);
        int h = n >> 7, dh = n & (DH_ - 1);
        s16x4 v4;
#pragma unroll
        for (int r = 0; r < 4; ++r) v4[r] = f2bf(acc[mi][ni][r]);
        *(s16x4*)&Vt[((size_t)((b * H_ + h) * DH_ + dh)) * T_ + t] = v4;
      }
  } else {
    // paths epilogue: sigmoid(z + bp), fp32, (B,H,T,DEPTH)
#pragma unroll
    for (int ni = 0; ni < 2; ++ni) {
      int pn = wn + ni * 16 + col;  // 0..63
      if (pn < H_ * DEPTH_) {
        float bias = bp[pn];
        int h = pn / DEPTH_, d = pn % DEPTH_;
#pragma unroll
        for (int mi = 0; mi < 2; ++mi)
#pragma unroll
          for (int r = 0; r < 4; ++r) {
            int m = bm + wm + mi * 16 + rbase + r;
            int b = m >> 10, t = m & (T_ - 1);
            float pv = 1.f / (1.f + __expf(-(acc[mi][ni][r] + bias)));
            paths_t[(((size_t)(b * H_ + h) * T_ + t) * DEPTH_) + d] = pv;
          }
      }
    }
  }
}

// -------------------------------------------------------------------------
// Fused causal p-adic attention, MFMA P.V.  512 threads / 8 waves.
// KT=128: 9 k-tiles per block-pair (qt/4 + (31-qt)/4 + 2 == 9 for all qt).
// V tile staged via global_load_lds into unpadded Vs[128][128] with XOR
// source swizzle (conflict-free DMA writes, 2-way frag reads).
// Wave w owns dh strip [w*16, w*16+16) and sim rows q0+w*4..+3; each lane
// computes sim for 2 k-columns. sim in [0,1] -> no max tracking.
// -------------------------------------------------------------------------
#define LS2 136

__global__ __launch_bounds__(512) void attn_kernel(
    const float* __restrict__ paths_t, const short* __restrict__ Vt,
    short* __restrict__ ctxb) {
  int bh = blockIdx.y;  // 0..15
  int b = bh >> 3, h = bh & 7;
  int bx = blockIdx.x;  // 0..15
  int w = threadIdx.x >> 6, lane = threadIdx.x & 63;
  int g = lane >> 4, fr = lane & 15;

  __shared__ short Vs[DH_ * 128];  // [dh][k] unpadded+swizzled, 32 KB
  __shared__ short Ss[32 * LS2];   // [q][k] padded 136, ~8.5 KB
  __shared__ float lsum_s[32];

  const float* pb = paths_t + (size_t)bh * T_ * DEPTH_;
  const short* vb = Vt + (size_t)bh * DH_ * T_;

  // glds addressing (per wave: 4 x 1KB covering rows w*16 .. w*16+15)
  int r4 = lane >> 4, cg = lane & 15;
  const short* Vsrc[4];
  short* Vdst[4];
#pragma unroll
  for (int i = 0; i < 4; ++i) {
    int row = w * 16 + i * 4 + r4;
    int scol = (cg ^ (row & 15)) * 8;
    Vsrc[i] = vb + (size_t)row * T_ + scol;
    Vdst[i] = &Vs[(w * 16 + i * 4) * 128];
  }

  for (int half = 0; half < 2; ++half) {
    int qt = half ? (31 - bx) : bx;
    int q0 = qt * 32;
    int nkt = (qt >> 2) + 1;  // KT=128 tiles; pair total = 9 always

    float pq[4][DEPTH_], mq[4][DEPTH_];
#pragma unroll
    for (int j = 0; j < 4; ++j) {
      const float* qr = pb + (size_t)(q0 + w * 4 + j) * DEPTH_;
#pragma unroll
      for (int d = 0; d < DEPTH_; ++d) {
        pq[j][d] = qr[d];
        mq[j][d] = 1.f - pq[j][d];
      }
    }
    f32x4 acc[2] = {{0.f, 0.f, 0.f, 0.f}, {0.f, 0.f, 0.f, 0.f}};
    float part[4] = {};

    for (int kt = 0; kt < nkt; ++kt) {
      int k0 = kt * 128;
      __syncthreads();  // prev MFMA readers / epilogue done
      // key-path loads first (oldest in vmcnt queue -> sim doesn't wait on glds)
      int kA = k0 + lane, kB = k0 + 64 + lane;
      const float* krA = pb + (size_t)kA * DEPTH_;
      const float* krB = pb + (size_t)kB * DEPTH_;
      float pkA[DEPTH_], mkA[DEPTH_], pkB[DEPTH_], mkB[DEPTH_];
#pragma unroll
      for (int d = 0; d < DEPTH_; ++d) {
        pkA[d] = krA[d];
        pkB[d] = krB[d];
      }
      // V tile DMA: 8 waves x 4 glds = 32 KB
#pragma unroll
      for (int i = 0; i < 4; ++i) glds16(Vsrc[i] + k0, Vdst[i]);
#pragma unroll
      for (int d = 0; d < DEPTH_; ++d) {
        mkA[d] = 1.f - pkA[d];
        mkB[d] = 1.f - pkB[d];
      }
#pragma unroll
      for (int j = 0; j < 4; ++j) {
        int qg = q0 + w * 4 + j;
        {
          float a0 = fmaf(pq[j][0], pkA[0], mq[j][0] * mkA[0]);
          float a1 = fmaf(pq[j][1], pkA[1], mq[j][1] * mkA[1]);
          float a2 = fmaf(pq[j][2], pkA[2], mq[j][2] * mkA[2]);
          float a3 = fmaf(pq[j][3], pkA[3], mq[j][3] * mkA[3]);
          float a4 = fmaf(pq[j][4], pkA[4], mq[j][4] * mkA[4]);
          float t4 = 1.f + a4;
          float t3 = fmaf(a3, t4, 1.f);
          float t2 = fmaf(a2, t3, 1.f);
          float t1 = fmaf(a1, t2, 1.f);
          float s = a0 * t1;
          float wv = (kA <= qg) ? __expf(s * 0.2f) : 0.f;
          part[j] += wv;
          Ss[(w * 4 + j) * LS2 + lane] = f2bf(wv);
        }
        {
          float a0 = fmaf(pq[j][0], pkB[0], mq[j][0] * mkB[0]);
          float a1 = fmaf(pq[j][1], pkB[1], mq[j][1] * mkB[1]);
          float a2 = fmaf(pq[j][2], pkB[2], mq[j][2] * mkB[2]);
          float a3 = fmaf(pq[j][3], pkB[3], mq[j][3] * mkB[3]);
          float a4 = fmaf(pq[j][4], pkB[4], mq[j][4] * mkB[4]);
          float t4 = 1.f + a4;
          float t3 = fmaf(a3, t4, 1.f);
          float t2 = fmaf(a2, t3, 1.f);
          float t1 = fmaf(a1, t2, 1.f);
          float s = a0 * t1;
          float wv = (kB <= qg) ? __expf(s * 0.2f) : 0.f;
          part[j] += wv;
          Ss[(w * 4 + j) * LS2 + 64 + lane] = f2bf(wv);
        }
      }
      __syncthreads();  // drains vmcnt (glds) + lgkm (Ss writes)
      // P @ V via MFMA: wave covers dh [16*w, 16*w+16); 4 ks steps of k32
#pragma unroll
      for (int ks = 0; ks < 4; ++ks) {
        int ko = ks * 32 + g * 8;
        int sl = ((ks * 4 + g) ^ fr) * 8;  // swizzled Vs slot (row&15 == fr)
        s16x8 sa0 = *(const s16x8*)&Ss[fr * LS2 + ko];
        s16x8 sa1 = *(const s16x8*)&Ss[(16 + fr) * LS2 + ko];
        s16x8 vv = *(const s16x8*)&Vs[(w * 16 + fr) * 128 + sl];
        acc[0] = MFMA16(sa0, vv, acc[0]);
        acc[1] = MFMA16(sa1, vv, acc[1]);
      }
    }
    // reduce per-q row sums across the wave's 64 lanes (each lane holds 2 k)
#pragma unroll
    for (int j = 0; j < 4; ++j) {
      float s = part[j];
#pragma unroll
      for (int off = 32; off >= 1; off >>= 1) s += __shfl_xor(s, off, 64);
      if (lane == j) lsum_s[w * 4 + j] = s;
    }
    __syncthreads();
    // epilogue: normalize, write bf16 ctx
    int col = fr, rbase = g * 4;
#pragma unroll
    for (int qt2 = 0; qt2 < 2; ++qt2)
#pragma unroll
      for (int r = 0; r < 4; ++r) {
        int ql = qt2 * 16 + rbase + r;
        int dh = w * 16 + col;
        float val = acc[qt2][r] / lsum_s[ql];
        ctxb[(size_t)(b * T_ + q0 + ql) * D_ + h * DH_ + dh] = f2bf(val);
      }
    __syncthreads();  // protect lsum_s before next half
  }
}

// -------------------------------------------------------------------------
extern "C" void kernel_launch(void* const* d_in, const int* in_sizes, int n_in,
                              void* d_out, int out_size, void* d_ws,
                              size_t ws_size, hipStream_t stream) {
  const float* x = (const float*)d_in[0];
  const float* Wp = (const float*)d_in[1];
  const float* bp = (const float*)d_in[2];
  const float* Wv = (const float*)d_in[3];
  const float* Wo = (const float*)d_in[4];
  float* out = (float*)d_out;

  char* ws = (char*)d_ws;
  float* paths_t = (float*)ws;           //   327,680 B
  short* Vt = (short*)(ws + 327680);     // 4,194,304 B bf16 [bh][dh][t]
  short* WBt = (short*)(ws + 4521984);   // 2,228,224 B bf16 [1088][1024]
  short* Wot = (short*)(ws + 6750208);   // 2,097,152 B bf16 [1024][1024]
  short* ctxb = (short*)(ws + 8847360);  // 4,194,304 B bf16 [2048][1024]
  short* xb = (short*)(ws + 13041664);   // 4,194,304 B bf16 [2048][1024]
  // total ~17.2 MB

  prep_kernel<<<dim3(16, 16, 3), 256, 0, stream>>>(Wv, Wo, Wp, x, WBt, Wot,
                                                   xb);
  gemm128<1><<<dim3(17, 32), 256, 0, stream>>>(xb, WBt, nullptr, Vt, bp,
                                               paths_t);
  attn_kernel<<<dim3(16, B_ * H_), 512, 0, stream>>>(paths_t, Vt, ctxb);
  gemm128<0><<<dim3(16, 32), 256, 0, stream>>>(ctxb, Wot, out, nullptr,
                                               nullptr, nullptr);
}